// Round 4
// baseline (113.928 us; speedup 1.0000x reference)
//
#include <hip/hip_runtime.h>
#include <hip/hip_bf16.h>

#define N_NODES 50000
#define NLAT 10
#define MU 32
#define BATCH 8
#define CHUNK 2000          // encode split-K chunk (floats)
#define NCHUNK 25
#define ENC_BLOCKS (BATCH * NLAT * NCHUNK)     // 2000
#define TR_BLOCKS ((N_NODES + 255) / 256)      // 196
#define DT_STRIDE 16        // floats per node in transposed decoder (64B line)
#define NPB 32              // nodes per main-kernel block
#define SG_MSTRIDE 388      // s_g m-row stride in floats (32*12 + 4): 16B-aligned, bank-staggered

// ---------------- Fused stage A: encode partials (blocks 0..1999) + decoder
// transpose (blocks 2000..2195).
__global__ __launch_bounds__(256) void encode_a_transpose(
    const float* __restrict__ x, const float* __restrict__ enc_w,
    const float* __restrict__ dec,
    float* __restrict__ partial, float* __restrict__ dec_t) {
    const int bid = blockIdx.x;
    if (bid < ENC_BLOCKS) {
        const int c  = bid % NCHUNK;
        const int bi = bid / NCHUNK;
        const int b = bi / NLAT, i = bi % NLAT;
        const float4* xr = (const float4*)(x + (size_t)b * N_NODES + c * CHUNK);
        const float4* wr = (const float4*)(enc_w + (size_t)i * N_NODES + c * CHUNK);
        float part = 0.0f;
        for (int q = threadIdx.x; q < CHUNK / 4; q += 256) {
            float4 xv = xr[q], wv = wr[q];
            part += xv.x * wv.x + xv.y * wv.y + xv.z * wv.z + xv.w * wv.w;
        }
        for (int off = 32; off; off >>= 1) part += __shfl_down(part, off, 64);
        __shared__ float s[4];
        if ((threadIdx.x & 63) == 0) s[threadIdx.x >> 6] = part;
        __syncthreads();
        if (threadIdx.x == 0) partial[bid] = (s[0] + s[1]) + (s[2] + s[3]);
    } else {
        const int p = (bid - ENC_BLOCKS) * 256 + threadIdx.x;
        if (p >= N_NODES) return;
        float v[DT_STRIDE];
        #pragma unroll
        for (int i = 0; i < NLAT; ++i) v[i] = dec[(size_t)i * N_NODES + p];
        #pragma unroll
        for (int i = NLAT; i < DT_STRIDE; ++i) v[i] = 0.0f;
        float4* dst = (float4*)(dec_t + (size_t)p * DT_STRIDE);
        #pragma unroll
        for (int q = 0; q < 4; ++q)
            dst[q] = make_float4(v[4*q], v[4*q+1], v[4*q+2], v[4*q+3]);
    }
}

// ---------------- Encode stage B: enc[b,i] = sum_c partial + bias
__global__ __launch_bounds__(128) void encode_stage_b(
    const float* __restrict__ partial, const float* __restrict__ enc_b,
    float* __restrict__ enc) {
    const int t = threadIdx.x;
    if (t < BATCH * NLAT) {
        float s = 0.0f;
        #pragma unroll
        for (int c = 0; c < NCHUNK; ++c) s += partial[t * NCHUNK + c];
        enc[t] = s + enc_b[t % NLAT];
    }
}

// ---------------- Main kernel: block = 32 nodes x 8 batches (tid = nl*8 + b).
// The 8 b-lanes of a node cooperatively gather dec_t lines into LDS once
// (instead of 8x duplicated), then each (node,b) thread does the window math
// reading LDS (same-address broadcast across its 8 b-lanes, bank-staggered
// across nodes).
__global__ __launch_bounds__(256) void nrbs_main_kernel(
    const float* __restrict__ dec_t,    // [N, 16]
    const float* __restrict__ bw,       // [n, n, N]
    const int*   __restrict__ nbr,      // [N, MU]
    const float* __restrict__ enc,      // [B, n]
    float*       __restrict__ out) {    // [B, N]
    __shared__ float s_enc[BATCH * NLAT];
    __shared__ float s_g[MU * SG_MSTRIDE];   // ~49.7 KB
    const int tid = threadIdx.x;
    if (tid < BATCH * NLAT) s_enc[tid] = enc[tid];
    __syncthreads();

    const int b  = tid & 7;
    const int nl = tid >> 3;                 // 0..31
    const int p  = blockIdx.x * NPB + nl;
    const bool act = (p < N_NODES);

    // inv[i] = 1/(sigmoid(z_i)*MU)^2 ; per-thread max support
    float inv[NLAT];
    float tmax = 0.0f;
    if (act) {
        const float* bwp = bw + p;
        #pragma unroll
        for (int i = 0; i < NLAT; ++i) {
            float z = 0.0f;
            #pragma unroll
            for (int k = 0; k < NLAT; ++k)
                z = fmaf(s_enc[b * NLAT + k],
                         bwp[(size_t)(i * NLAT + k) * N_NODES], z);
            const float w = 1.0f / (1.0f + __expf(-z));
            const float t = w * (float)MU;
            tmax = fmaxf(tmax, t);
            inv[i] = 1.0f / (t * t);
        }
    }
    // node-wide support cap: max over the node's 8 contiguous b-lanes
    float tm = tmax;
    tm = fmaxf(tm, __shfl_xor(tm, 1, 64));
    tm = fmaxf(tm, __shfl_xor(tm, 2, 64));
    tm = fmaxf(tm, __shfl_xor(tm, 4, 64));
    const int mcap = min(MU, (int)tm + 1);   // win=0 for all (b,i) when m >= mcap

    // cooperative gather: lane b handles m = b, b+8, b+16, b+24 (< mcap)
    if (act) {
        #pragma unroll
        for (int j = 0; j < 4; ++j) {
            const int m = b + 8 * j;
            if (m < mcap) {
                const int idx = nbr[(size_t)p * MU + m];
                const float4* gp = (const float4*)(dec_t + (size_t)idx * DT_STRIDE);
                const float4 g0 = gp[0], g1 = gp[1], g2 = gp[2];
                float4* dst = (float4*)(s_g + m * SG_MSTRIDE + nl * 12);
                dst[0] = g0; dst[1] = g1; dst[2] = g2;   // 12 floats (2 pad)
            }
        }
    }
    __syncthreads();   // block-wide: all writes visible (uniform control flow)

    if (!act) return;

    float asum[NLAT], ssum[NLAT];
    #pragma unroll
    for (int i = 0; i < NLAT; ++i) { asum[i] = 0.0f; ssum[i] = 0.0f; }

    for (int m = 0; m < mcap; ++m) {
        const float m2 = (float)(m * m);
        const float* gr = s_g + m * SG_MSTRIDE + nl * 12;
        const float4 ga = *(const float4*)(gr);
        const float4 gb = *(const float4*)(gr + 4);
        const float2 gc = *(const float2*)(gr + 8);
        const float g[NLAT] = {ga.x, ga.y, ga.z, ga.w,
                               gb.x, gb.y, gb.z, gb.w, gc.x, gc.y};
        #pragma unroll
        for (int i = 0; i < NLAT; ++i) {
            const float win = fmaxf(0.0f, fmaf(-m2, inv[i], 1.0f));
            ssum[i] += win;
            asum[i] = fmaf(g[i], win, asum[i]);
        }
    }

    float acc = 0.0f;
    #pragma unroll
    for (int i = 0; i < NLAT; ++i)
        acc = fmaf(s_enc[b * NLAT + i], asum[i] / ssum[i], acc);
    out[(size_t)b * N_NODES + p] = acc;
}

extern "C" void kernel_launch(void* const* d_in, const int* in_sizes, int n_in,
                              void* d_out, int out_size, void* d_ws, size_t ws_size,
                              hipStream_t stream) {
    const float* x       = (const float*)d_in[0];   // [B, N]
    const float* enc_w   = (const float*)d_in[1];   // [n, N]
    const float* enc_b   = (const float*)d_in[2];   // [n]
    const float* decoder = (const float*)d_in[3];   // [n, N]
    const float* bwl     = (const float*)d_in[4];   // [n, n, N]
    const int*   nbr     = (const int*)d_in[5];     // [N, MU]
    float* out = (float*)d_out;                     // [B, N]

    float* enc     = (float*)d_ws;                   // 80 floats
    float* partial = (float*)((char*)d_ws + 1024);   // 2000 floats
    float* dec_t   = (float*)((char*)d_ws + 65536);  // 3.2 MB

    encode_a_transpose<<<ENC_BLOCKS + TR_BLOCKS, 256, 0, stream>>>(
        x, enc_w, decoder, partial, dec_t);
    encode_stage_b<<<1, 128, 0, stream>>>(partial, enc_b, enc);

    const int blocks = (N_NODES + NPB - 1) / NPB;   // 1563
    nrbs_main_kernel<<<blocks, 256, 0, stream>>>(dec_t, bwl, nbr, enc, out);
}

// Round 5
// 110.740 us; speedup vs baseline: 1.0288x; 1.0288x over previous
//
#include <hip/hip_runtime.h>
#include <hip/hip_bf16.h>

#define N_NODES 50000
#define NLAT 10
#define MU 32
#define BATCH 8
#define CHUNK 2000          // encode split-K chunk (floats)
#define NCHUNK 25
#define ENC_BLOCKS (BATCH * NLAT * NCHUNK)     // 2000
#define TR_BLOCKS ((N_NODES + 255) / 256)      // 196
#define DT_STRIDE 16        // floats per node in transposed decoder (64B line)
#define NPB 64              // nodes per main-kernel block
#define INV_STRIDE (NPB + 2)   // 66: bank-staggered leading dim for s_inv

// ---------------- Kernel 1: encode partials (blocks 0..1999) + decoder
// transpose (blocks 2000..2195). Partial/x/w chunks are L2-resident across
// the concurrent blocks, so the 8x/10x logical re-reads are cheap.
__global__ __launch_bounds__(256) void encode_a_transpose(
    const float* __restrict__ x, const float* __restrict__ enc_w,
    const float* __restrict__ dec,
    float* __restrict__ partial, float* __restrict__ dec_t) {
    const int bid = blockIdx.x;
    if (bid < ENC_BLOCKS) {
        const int c  = bid % NCHUNK;
        const int bi = bid / NCHUNK;
        const int b = bi / NLAT, i = bi % NLAT;
        const float4* xr = (const float4*)(x + (size_t)b * N_NODES + c * CHUNK);
        const float4* wr = (const float4*)(enc_w + (size_t)i * N_NODES + c * CHUNK);
        float part = 0.0f;
        for (int q = threadIdx.x; q < CHUNK / 4; q += 256) {
            float4 xv = xr[q], wv = wr[q];
            part += xv.x * wv.x + xv.y * wv.y + xv.z * wv.z + xv.w * wv.w;
        }
        for (int off = 32; off; off >>= 1) part += __shfl_down(part, off, 64);
        __shared__ float s[4];
        if ((threadIdx.x & 63) == 0) s[threadIdx.x >> 6] = part;
        __syncthreads();
        if (threadIdx.x == 0) partial[bid] = (s[0] + s[1]) + (s[2] + s[3]);
    } else {
        const int p = (bid - ENC_BLOCKS) * 256 + threadIdx.x;
        if (p >= N_NODES) return;
        float v[DT_STRIDE];
        #pragma unroll
        for (int i = 0; i < NLAT; ++i) v[i] = dec[(size_t)i * N_NODES + p];
        #pragma unroll
        for (int i = NLAT; i < DT_STRIDE; ++i) v[i] = 0.0f;
        float4* dst = (float4*)(dec_t + (size_t)p * DT_STRIDE);
        #pragma unroll
        for (int q = 0; q < 4; ++q)
            dst[q] = make_float4(v[4*q], v[4*q+1], v[4*q+2], v[4*q+3]);
    }
}

// ---------------- Kernel 2: fused main. Block = 64 nodes, 512 threads.
//  Prologue: threads 0..79 reduce encode partials -> s_enc (replaces stage B).
//  Phase 1 (wave g owns latent i = g, g+8): bw loads fully coalesced
//           (lane = node), inv[b,i,node] -> LDS, per-node tmax via atomicMax.
//  Phase 2 (thread = (node, b)): dec_t gathers + window accumulation.
__global__ __launch_bounds__(512) void nrbs_main_kernel(
    const float* __restrict__ dec_t,    // [N, 16]
    const float* __restrict__ bw,       // [n, n, N]
    const int*   __restrict__ nbr,      // [N, MU]
    const float* __restrict__ partial,  // [B*n, NCHUNK]
    const float* __restrict__ enc_b,    // [n]
    float*       __restrict__ out) {    // [B, N]
    __shared__ float s_enc[BATCH * NLAT];
    __shared__ float s_inv[BATCH * NLAT * INV_STRIDE];   // 21120 B
    __shared__ int   s_tm[NPB];
    const int tid = threadIdx.x;

    if (tid < BATCH * NLAT) {
        float s = 0.0f;
        #pragma unroll
        for (int c = 0; c < NCHUNK; ++c) s += partial[tid * NCHUNK + c];
        s_enc[tid] = s + enc_b[tid % NLAT];
    }
    if (tid < NPB) s_tm[tid] = 0;
    __syncthreads();

    // ---- Phase 1: coalesced bw reads, one wave per latent-i slot
    {
        const int g    = tid >> 6;        // wave id 0..7
        const int lane = tid & 63;        // node within block
        const int p    = blockIdx.x * NPB + lane;
        if (p < N_NODES) {
            float tloc = 0.0f;
            for (int i = g; i < NLAT; i += 8) {
                float bwv[NLAT];
                #pragma unroll
                for (int k = 0; k < NLAT; ++k)
                    bwv[k] = bw[((size_t)(i * NLAT + k)) * N_NODES + p];
                #pragma unroll
                for (int b = 0; b < BATCH; ++b) {
                    float z = 0.0f;
                    #pragma unroll
                    for (int k = 0; k < NLAT; ++k)
                        z = fmaf(s_enc[b * NLAT + k], bwv[k], z);
                    const float w = 1.0f / (1.0f + __expf(-z));
                    const float t = w * (float)MU;
                    tloc = fmaxf(tloc, t);
                    s_inv[(b * NLAT + i) * INV_STRIDE + lane] = 1.0f / (t * t);
                }
            }
            atomicMax(&s_tm[lane], __float_as_int(tloc));  // t>0: bits ordered
        }
    }
    __syncthreads();

    // ---- Phase 2: thread = (node, batch)
    const int b  = tid & 7;
    const int nl = tid >> 3;              // 0..63
    const int p  = blockIdx.x * NPB + nl;
    if (p >= N_NODES) return;

    const int mcap = min(MU, (int)__int_as_float(s_tm[nl]) + 1);

    float inv[NLAT];
    #pragma unroll
    for (int i = 0; i < NLAT; ++i)
        inv[i] = s_inv[(b * NLAT + i) * INV_STRIDE + nl];

    float asum[NLAT], ssum[NLAT];
    #pragma unroll
    for (int i = 0; i < NLAT; ++i) { asum[i] = 0.0f; ssum[i] = 0.0f; }

    const int4* nb4 = (const int4*)(nbr + (size_t)p * MU);
    for (int q = 0; 4 * q < mcap; ++q) {   // padded chunks: extra m give win=0
        const int4 v = nb4[q];
        const int idx[4] = {v.x, v.y, v.z, v.w};
        #pragma unroll
        for (int j = 0; j < 4; ++j) {
            const int m = 4 * q + j;
            const float m2 = (float)(m * m);
            const float4* gp = (const float4*)(dec_t + (size_t)idx[j] * DT_STRIDE);
            const float4 g0 = gp[0], g1 = gp[1];
            const float2 g2 = *(const float2*)(&gp[2]);
            const float g[NLAT] = {g0.x, g0.y, g0.z, g0.w,
                                   g1.x, g1.y, g1.z, g1.w, g2.x, g2.y};
            #pragma unroll
            for (int i = 0; i < NLAT; ++i) {
                const float win = fmaxf(0.0f, fmaf(-m2, inv[i], 1.0f));
                ssum[i] += win;
                asum[i] = fmaf(g[i], win, asum[i]);
            }
        }
    }

    float acc = 0.0f;
    #pragma unroll
    for (int i = 0; i < NLAT; ++i)
        acc = fmaf(s_enc[b * NLAT + i], asum[i] / ssum[i], acc);
    out[(size_t)b * N_NODES + p] = acc;
}

extern "C" void kernel_launch(void* const* d_in, const int* in_sizes, int n_in,
                              void* d_out, int out_size, void* d_ws, size_t ws_size,
                              hipStream_t stream) {
    const float* x       = (const float*)d_in[0];   // [B, N]
    const float* enc_w   = (const float*)d_in[1];   // [n, N]
    const float* enc_b   = (const float*)d_in[2];   // [n]
    const float* decoder = (const float*)d_in[3];   // [n, N]
    const float* bwl     = (const float*)d_in[4];   // [n, n, N]
    const int*   nbr     = (const int*)d_in[5];     // [N, MU]
    float* out = (float*)d_out;                     // [B, N]

    float* partial = (float*)((char*)d_ws + 1024);   // 2000 floats
    float* dec_t   = (float*)((char*)d_ws + 65536);  // 3.2 MB

    encode_a_transpose<<<ENC_BLOCKS + TR_BLOCKS, 256, 0, stream>>>(
        x, enc_w, decoder, partial, dec_t);

    const int blocks = (N_NODES + NPB - 1) / NPB;   // 782
    nrbs_main_kernel<<<blocks, 512, 0, stream>>>(
        dec_t, bwl, nbr, partial, enc_b, out);
}